// Round 5
// baseline (254.670 us; speedup 1.0000x reference)
//
#include <hip/hip_runtime.h>

// SpectralConv2d: B=16, C_in=C_out=64, H=W=256, k=16.
// Retained modes: rows {0..15, 240..255} x cols {0..15} -> direct sparse DFTs.
//
// Pipeline (fp32):
//  k_twiddle : cos/sin(2*pi*t/256) tables -> ws
//  k_repack  : R'[c][o][m][wm] = (Wre + i Wim) * (wm==0?1:2)/65536   (coalesced)
//  k_fwd     : FUSED x-DFT + y-DFT per (b,c) image, streamed in 8 chunks
//              -> U[mw][b*64+c]  (no P intermediate in HBM)
//  k_cgemm   : per (m,wm): V[b][o] = sum_c U[b][c]*R'[c][o]  (complex)
//  k_inv     : inverse y-DFT (4 quarters/rotation) + x reconstruction -> out

#define B_    16
#define H_    256
#define W_    256

// ws float offsets
#define OFF_CT 0
#define OFF_ST 256
#define OFF_RP 512
#define RP_SZ  (4096*512*2)                  // 4,194,304
#define OFF_U  (OFF_RP + RP_SZ)              // 4,194,816
#define U_SZ   (512*1024*2)                  // 1,048,576
#define OFF_V  (OFF_U + U_SZ)                // 5,243,392

typedef const __attribute__((address_space(1))) void g_void;
typedef __attribute__((address_space(3))) void l_void;

__device__ __forceinline__ void load_lds16(const float* g, float* l) {
    __builtin_amdgcn_global_load_lds((g_void*)g, (l_void*)l, 16, 0, 0);
}

__global__ void k_twiddle(float* __restrict__ ws) {
    int t = threadIdx.x;
    double a = 2.0 * 3.14159265358979323846 * (double)t / 256.0;
    ws[OFF_CT + t] = (float)cos(a);
    ws[OFF_ST + t] = (float)sin(a);
}

// grid 4096 = (c*64+o); fully coalesced read and write.
__global__ __launch_bounds__(256) void k_repack(const float* __restrict__ wpr,
                                                const float* __restrict__ wpi,
                                                const float* __restrict__ wnr,
                                                const float* __restrict__ wni,
                                                float* __restrict__ ws) {
    int co = blockIdx.x, t = threadIdx.x;      // t = i*16 + wm
    int wm = t & 15;
    float norm = (wm == 0 ? 1.f : 2.f) * (1.f / 65536.f);
    size_t src = (size_t)co * 256 + t;
    float2* rp = (float2*)(ws + OFF_RP) + (size_t)co * 512;
    rp[t]       = make_float2(wpr[src] * norm, wpi[src] * norm);   // m = i
    rp[t + 256] = make_float2(wnr[src] * norm, wni[src] * norm);   // m = i+16
}

// FUSED forward. grid 1024 = bc, block 256.
// Per chunk (32 rows): stage1 x-DFT (threads = 32 yl x 8 h, modes 2h,2h+1)
// into Pl; stage2 consumes Pl into per-thread y-DFT accumulators
// (threads = 16 m-pairs x 16 wm, 256-step phase recurrence across chunks).
__global__ __launch_bounds__(256) void k_fwd(const float* __restrict__ u,
                                             const float* __restrict__ ws,
                                             float* __restrict__ U) {
    __shared__ __align__(16) float ut[32][256];   // 32 KB image chunk
    __shared__ __align__(16) float Pl[32][36];    // chunk P: [yl][2*wm+{re,im}]
    __shared__ float ct[256], st[256];
    int t = threadIdx.x, bc = blockIdx.x;
    ct[t] = ws[OFF_CT + t];
    st[t] = ws[OFF_ST + t];
    const float* ub = u + (size_t)bc * 65536;
    int lane = t & 63, w = t >> 6;

    // prologue: stage chunk 0 (touches only ut, not ct/st)
    #pragma unroll
    for (int k = 0; k < 8; ++k) {
        int row = w * 8 + k;
        load_lds16(ub + row * 256 + lane * 4, &ut[row][0]);
    }
    // RACE FIX (R4): twiddle-setup below reads ct/st entries written by OTHER
    // waves — must barrier after the table writes before any cross-thread read.
    __syncthreads();

    // stage-1 thread mapping (x-DFT): x = j + 64k, twiddle(x)=twiddle(j)*(-i)^(wm*k)
    int yl = t & 31, h = t >> 5;
    int wm0 = 2 * h, wm1 = wm0 + 1;
    int j0 = 2 * yl;                                   // bank-stagger start
    float r0r = ct[wm0], r0i = -st[wm0];
    float r1r = ct[wm1], r1i = -st[wm1];
    float t0r0 = ct[(wm0 * j0) & 255], t0i0 = -st[(wm0 * j0) & 255];
    float t1r0 = ct[(wm1 * j0) & 255], t1i0 = -st[(wm1 * j0) & 255];
    float bs  = (h & 1) ? -1.f : 1.f;                  // (-i)^(2h*k) = (-1)^(hk)
    float dsg = (h & 1) ? 1.f : -1.f;                  // g1 = c -/+ i d

    // stage-2 thread mapping (y-DFT): modes f=m1 and f=m1-16
    int wm = t & 15, m1 = t >> 4;
    float q1r = ct[m1], q1i = -st[m1];                 // e^{-2pi i m1/256}
    int m2i = (16 - m1) & 255;
    float q2r = ct[m2i], q2i = st[m2i];                // e^{-2pi i (m1-16)/256}
    float w1r = 1.f, w1i = 0.f, w2r = 1.f, w2i = 0.f;  // phase at y=0
    float U1r = 0.f, U1i = 0.f, U2r = 0.f, U2i = 0.f;

    for (int ch = 0; ch < 8; ++ch) {
        asm volatile("s_waitcnt vmcnt(0)" ::: "memory");
        __syncthreads();                               // ut[ch] ready; Pl free

        // ---- stage 1: x-DFT on 32 rows ----
        float t0r = t0r0, t0i = t0i0, t1r = t1r0, t1i = t1i0;
        float p0r = 0.f, p0i = 0.f, p1r = 0.f, p1i = 0.f;
        const float* row = &ut[yl][0];
        #pragma unroll 8
        for (int s = 0; s < 64; ++s) {
            int j = j0 + s;                            // <= 125
            float u0 = row[j], u1 = row[j + 64], u2 = row[j + 128];
            float u3 = row[(j + 192) & 255];
            float a = u0 + u2, b = u1 + u3, c = u0 - u2, d = u1 - u3;
            float g0 = fmaf(bs, b, a);
            float g1r = c, g1i = dsg * d;
            p0r = fmaf(g0, t0r, p0r);
            p0i = fmaf(g0, t0i, p0i);
            p1r = fmaf(g1r, t1r, fmaf(-g1i, t1i, p1r));
            p1i = fmaf(g1r, t1i, fmaf( g1i, t1r, p1i));
            float n0r = t0r * r0r - t0i * r0i, n0i = t0r * r0i + t0i * r0r;
            float n1r = t1r * r1r - t1i * r1i, n1i = t1r * r1i + t1i * r1r;
            t0r = n0r; t0i = n0i; t1r = n1r; t1i = n1i;
        }
        *(float4*)&Pl[yl][4 * h] = make_float4(p0r, p0i, p1r, p1i);
        __syncthreads();                               // Pl ready; ut free

        // prefetch next chunk (overwrites ut; all stage-1 readers are done)
        if (ch < 7) {
            const float* ub2 = ub + (ch + 1) * 8192;
            #pragma unroll
            for (int k = 0; k < 8; ++k) {
                int rw = w * 8 + k;
                load_lds16(ub2 + rw * 256 + lane * 4, &ut[rw][0]);
            }
        }

        // ---- stage 2: accumulate 32 y of the y-DFT ----
        #pragma unroll 4
        for (int yy = 0; yy < 32; ++yy) {
            float2 g = *(float2*)&Pl[yy][2 * wm];
            U1r = fmaf(g.x, w1r, fmaf(-g.y, w1i, U1r));
            U1i = fmaf(g.x, w1i, fmaf( g.y, w1r, U1i));
            U2r = fmaf(g.x, w2r, fmaf(-g.y, w2i, U2r));
            U2i = fmaf(g.x, w2i, fmaf( g.y, w2r, U2i));
            float n1r = w1r * q1r - w1i * q1i, n1i = w1r * q1i + w1i * q1r;
            float n2r = w2r * q2r - w2i * q2i, n2i = w2r * q2i + w2i * q2r;
            w1r = n1r; w1i = n1i; w2r = n2r; w2i = n2i;
        }
    }

    float2* Ug = (float2*)U;
    Ug[(size_t)(m1 * 16 + wm) * 1024 + bc]        = make_float2(U1r, U1i);
    Ug[(size_t)((m1 + 16) * 16 + wm) * 1024 + bc] = make_float2(U2r, U2i);
}

// per-mode channel GEMM: grid 512 = mw
__global__ __launch_bounds__(256) void k_cgemm(float* __restrict__ ws) {
    __shared__ float2 Ul[1024];
    int mw = blockIdx.x, t = threadIdx.x;
    const float2* Ug = (const float2*)(ws + OFF_U) + (size_t)mw * 1024;
    #pragma unroll
    for (int k = 0; k < 4; ++k) Ul[t + 256 * k] = Ug[t + 256 * k];
    __syncthreads();
    int o = t & 63, bq = t >> 6;
    const float2* rp = (const float2*)(ws + OFF_RP);
    float ar[4] = {0.f, 0.f, 0.f, 0.f}, ai[4] = {0.f, 0.f, 0.f, 0.f};
    #pragma unroll 4
    for (int c = 0; c < 64; ++c) {
        float2 R = rp[(size_t)(c * 64 + o) * 512 + mw];
        #pragma unroll
        for (int j = 0; j < 4; ++j) {
            float2 Uv = Ul[(bq * 4 + j) * 64 + c];     // wave-uniform -> broadcast
            ar[j] = fmaf(Uv.x, R.x, fmaf(-Uv.y, R.y, ar[j]));
            ai[j] = fmaf(Uv.x, R.y, fmaf( Uv.y, R.x, ai[j]));
        }
    }
    float2* Vg = (float2*)(ws + OFF_V);
    #pragma unroll
    for (int j = 0; j < 4; ++j)
        Vg[(size_t)((bq * 4 + j) * 64 + o) * 512 + mw] = make_float2(ar[j], ai[j]);
}

// inverse. grid 4096 = (bo, q); block covers y in {q*16+yb + 64g}.
__global__ __launch_bounds__(256) void k_inv(const float* __restrict__ ws,
                                             float* __restrict__ out) {
    __shared__ float Vl[16][68];
    __shared__ float Tl[4][16][36];
    __shared__ float ct[256], st[256];
    int t = threadIdx.x;
    int bo = blockIdx.x >> 2, q = blockIdx.x & 3;
    ct[t] = ws[OFF_CT + t];
    st[t] = ws[OFF_ST + t];
    {
        // V[bo] has 512 complex entries (32 m x 16 wm): load BOTH halves.
        const float2* Vg = (const float2*)(ws + OFF_V) + (size_t)bo * 512;
        float2 v0 = Vg[t];
        float2 v1 = Vg[t + 256];
        int m = t >> 4, wmv = t & 15;
        Vl[wmv][2 * m]        = v0.x;  Vl[wmv][2 * m + 1]        = v0.y;
        Vl[wmv][2 * (m + 16)] = v1.x;  Vl[wmv][2 * (m + 16) + 1] = v1.y;
    }
    __syncthreads();

    // stage 4: T[y0+64g] = sum_m V[m] e^{+2pi i f y0/256} * i^(f g)
    int wm4 = t & 15, yb = t >> 4;
    int y0 = q * 16 + yb;
    float vr[32], vi[32];
    #pragma unroll
    for (int m = 0; m < 32; ++m) { vr[m] = Vl[wm4][2 * m]; vi[m] = Vl[wm4][2 * m + 1]; }
    float cy = ct[y0], sy = st[y0];
    float T0r=0,T0i=0,T1r=0,T1i=0,T2r=0,T2i=0,T3r=0,T3i=0;
    float tr = 1.f, ti = 0.f;
    #pragma unroll
    for (int m = 0; m < 32; ++m) {
        if (m == 16) {
            int i16 = (4096 - 16 * y0) & 255;          // e^{-2pi i 16 y0/256}
            tr = ct[i16]; ti = st[i16];
        }
        float hr = vr[m] * tr - vi[m] * ti;
        float hi = vr[m] * ti + vi[m] * tr;
        const int md = m & 3;
        T0r += hr; T0i += hi;
        if (md == 0)      { T1r += hr; T1i += hi; T2r += hr; T2i += hi; T3r += hr; T3i += hi; }
        else if (md == 1) { T1r -= hi; T1i += hr; T2r -= hr; T2i -= hi; T3r += hi; T3i -= hr; }
        else if (md == 2) { T1r -= hr; T1i -= hi; T2r += hr; T2i += hi; T3r -= hr; T3i -= hi; }
        else              { T1r += hi; T1i -= hr; T2r -= hr; T2i -= hi; T3r -= hi; T3i += hr; }
        float nr = tr * cy - ti * sy, ni = tr * sy + ti * cy;
        tr = nr; ti = ni;
    }
    Tl[0][yb][wm4] = T0r; Tl[0][yb][16 + wm4] = T0i;
    Tl[1][yb][wm4] = T1r; Tl[1][yb][16 + wm4] = T1i;
    Tl[2][yb][wm4] = T2r; Tl[2][yb][16 + wm4] = T2i;
    Tl[3][yb][wm4] = T3r; Tl[3][yb][16 + wm4] = T3i;
    __syncthreads();

    // stage 5: out[y][64k+l] = sum_wm Re{(TR+iTI) e^{+i th wm(l+64k)}}
    int l = t & 63, wv = t >> 6;
    float c0[16], s0[16];
    #pragma unroll
    for (int wm = 0; wm < 16; ++wm) {
        int idx = (wm * l) & 255;
        c0[wm] = ct[idx]; s0[wm] = st[idx];
    }
    float* ob = out + (size_t)bo * 65536;
    for (int yi = 0; yi < 16; ++yi) {
        int y = wv * 64 + q * 16 + yi;
        float TR[16], TI[16];
        const float4* rowv = (const float4*)&Tl[wv][yi][0];
        #pragma unroll
        for (int qq = 0; qq < 4; ++qq) {
            float4 a = rowv[qq];
            TR[4*qq]=a.x; TR[4*qq+1]=a.y; TR[4*qq+2]=a.z; TR[4*qq+3]=a.w;
            float4 b = rowv[qq + 4];
            TI[4*qq]=b.x; TI[4*qq+1]=b.y; TI[4*qq+2]=b.z; TI[4*qq+3]=b.w;
        }
        #pragma unroll
        for (int k = 0; k < 4; ++k) {
            float a = 0.f;
            #pragma unroll
            for (int wm = 0; wm < 16; ++wm) {
                int p = (k * wm) & 3;
                if (p == 0)      a +=  TR[wm] * c0[wm] - TI[wm] * s0[wm];
                else if (p == 1) a += -TR[wm] * s0[wm] - TI[wm] * c0[wm];
                else if (p == 2) a += -TR[wm] * c0[wm] + TI[wm] * s0[wm];
                else             a +=  TR[wm] * s0[wm] + TI[wm] * c0[wm];
            }
            ob[(size_t)y * 256 + 64 * k + l] = a;
        }
    }
}

extern "C" void kernel_launch(void* const* d_in, const int* in_sizes, int n_in,
                              void* d_out, int out_size, void* d_ws, size_t ws_size,
                              hipStream_t stream) {
    const float* u   = (const float*)d_in[0];
    const float* wpr = (const float*)d_in[1];
    const float* wpi = (const float*)d_in[2];
    const float* wnr = (const float*)d_in[3];
    const float* wni = (const float*)d_in[4];
    float* out = (float*)d_out;
    float* ws  = (float*)d_ws;

    hipLaunchKernelGGL(k_twiddle, dim3(1),    dim3(256), 0, stream, ws);
    hipLaunchKernelGGL(k_repack,  dim3(4096), dim3(256), 0, stream, wpr, wpi, wnr, wni, ws);
    hipLaunchKernelGGL(k_fwd,     dim3(1024), dim3(256), 0, stream, u, ws, ws + OFF_U);
    hipLaunchKernelGGL(k_cgemm,   dim3(512),  dim3(256), 0, stream, ws);
    hipLaunchKernelGGL(k_inv,     dim3(4096), dim3(256), 0, stream, ws, out);
}